// Round 4
// baseline (1134.361 us; speedup 1.0000x reference)
//
#include <hip/hip_runtime.h>
#include <cstdint>
#include <cstddef>

typedef __attribute__((ext_vector_type(8))) _Float16 half8;
typedef __attribute__((ext_vector_type(4))) _Float16 half4;
typedef __attribute__((ext_vector_type(4))) float f32x4;

#define DEV static __device__ __forceinline__

DEV half8 cvt8(const float* p) {
    f32x4 a = *(const f32x4*)p;
    f32x4 b = *(const f32x4*)(p + 4);
    half8 o;
    o[0] = (_Float16)a[0]; o[1] = (_Float16)a[1];
    o[2] = (_Float16)a[2]; o[3] = (_Float16)a[3];
    o[4] = (_Float16)b[0]; o[5] = (_Float16)b[1];
    o[6] = (_Float16)b[2]; o[7] = (_Float16)b[3];
    return o;
}

DEV half8 sum8(const _Float16* p0, const _Float16* p1) {
    half8 x = *(const half8*)p0;
    half8 y = *(const half8*)p1;
    half8 o;
#pragma unroll
    for (int i = 0; i < 8; i++) o[i] = (_Float16)((float)x[i] + (float)y[i]);
    return o;
}

// C[M,N] = (A * B[N,K]^T + bias) * scale
// AMODE: 0 = f32 (convert during staging), 1 = f16, 2 = f16 sum of two buffers.
template<int BM, int BN, int WR, int WC, int AMODE, bool OUT_F16, bool OUT_TRANS>
__global__ __launch_bounds__(256, 2)
void gemm_bt(const void* __restrict__ Aptr, const void* __restrict__ Aptr2,
             const float* __restrict__ Bw, const float* __restrict__ bias, float scale,
             void* __restrict__ Cout, int M, int N, int K)
{
    constexpr int BK = 32;
    constexpr int WM = BM / WR, WN = BN / WC;
    constexpr int MF = WM / 16, NF = WN / 16;
    constexpr int LDT = 40;
    __shared__ _Float16 As[BM][LDT];
    __shared__ _Float16 Bs[BN][LDT];

    const int tid = threadIdx.x;
    const int l = tid & 63, w = tid >> 6;
    const int wr = w / WC, wc = w % WC;
    const int lr = l & 15, lh = l >> 4;
    const int bm0 = blockIdx.y * BM, bn0 = blockIdx.x * BN;

    f32x4 acc[MF][NF] = {};

    for (int k0 = 0; k0 < K; k0 += BK) {
        __syncthreads();
        for (int c = tid; c < BM * 4; c += 256) {
            int row = c >> 2, c8 = (c & 3) << 3;
            size_t off = (size_t)(bm0 + row) * K + k0 + c8;
            if constexpr (AMODE == 1) {
                *(half8*)&As[row][c8] = *(const half8*)((const _Float16*)Aptr + off);
            } else if constexpr (AMODE == 2) {
                *(half8*)&As[row][c8] = sum8((const _Float16*)Aptr + off,
                                             (const _Float16*)Aptr2 + off);
            } else {
                *(half8*)&As[row][c8] = cvt8((const float*)Aptr + off);
            }
        }
        for (int c = tid; c < BN * 4; c += 256) {
            int row = c >> 2, c8 = (c & 3) << 3;
            const float* bp = Bw + (size_t)(bn0 + row) * K + k0 + c8;
            *(half8*)&Bs[row][c8] = cvt8(bp);
        }
        __syncthreads();

        half8 a[MF], b[NF];
#pragma unroll
        for (int m = 0; m < MF; m++)
            a[m] = *(const half8*)&As[wr * WM + m * 16 + lr][lh * 8];
#pragma unroll
        for (int n = 0; n < NF; n++)
            b[n] = *(const half8*)&Bs[wc * WN + n * 16 + lr][lh * 8];
#pragma unroll
        for (int m = 0; m < MF; m++)
#pragma unroll
            for (int n = 0; n < NF; n++)
                acc[m][n] = __builtin_amdgcn_mfma_f32_16x16x32_f16(a[m], b[n], acc[m][n], 0, 0, 0);
    }

#pragma unroll
    for (int m = 0; m < MF; m++)
#pragma unroll
        for (int n = 0; n < NF; n++) {
            int row0 = bm0 + wr * WM + m * 16 + lh * 4;
            int col = bn0 + wc * WN + n * 16 + lr;
            float bv = bias[col];
#pragma unroll
            for (int j = 0; j < 4; j++) {
                float val = (acc[m][n][j] + bv) * scale;
                int row = row0 + j;
                if constexpr (OUT_TRANS) {
                    int bi = row >> 11, t = row & 2047;
                    ((_Float16*)Cout)[(((size_t)(bi * 64 + col)) << 11) + t] = (_Float16)val;
                } else if constexpr (OUT_F16) {
                    ((_Float16*)Cout)[(size_t)row * N + col] = (_Float16)val;
                } else {
                    ((float*)Cout)[(size_t)row * N + col] = val;
                }
            }
        }
}

// ---- Stats kernel: softmax denominators, barrier-free, zero LDS, max TLP ----
// Grid 1024: b=blk&3, ks=(blk>>2)&1 (k-half), q-tile=(blk>>3)*16 rows.
// 8 waves x 2 heads; partial sum over half the k-range; butterfly over lr;
// writes sl_p[ks][b][h][q].
__global__ __launch_bounds__(512, 8)
void stats_kernel(const _Float16* __restrict__ Qh, const _Float16* __restrict__ Kh,
                  float* __restrict__ sl_p)
{
    const int blk = blockIdx.x;
    const int b = blk & 3;
    const int ks = (blk >> 2) & 1;
    const int q0 = (blk >> 3) << 4;
    const int tid = threadIdx.x;
    const int l = tid & 63, w = tid >> 6;
    const int lr = l & 15, lh = l >> 4;
    const int h0 = w << 1;

    const size_t base = (size_t)b * 2048 * 1024;
    const _Float16* Qb = Qh + base;
    const _Float16* Kb = Kh + base;

    half8 qf[2][2];
#pragma unroll
    for (int hh = 0; hh < 2; hh++)
#pragma unroll
        for (int dk = 0; dk < 2; dk++)
            qf[hh][dk] = *(const half8*)(Qb + (size_t)(q0 + lr) * 1024
                                         + (h0 + hh) * 64 + dk * 32 + lh * 8);

    float sl[2][4] = {};
    const int kend = ks * 32 + 32;
    for (int kt = ks * 32; kt < kend; kt++) {
        const _Float16* kp = Kb + (size_t)(kt * 32) * 1024;
#pragma unroll
        for (int hh = 0; hh < 2; hh++) {
            half8 kfh[2][2];
#pragma unroll
            for (int kfr = 0; kfr < 2; kfr++)
#pragma unroll
                for (int dk = 0; dk < 2; dk++)
                    kfh[kfr][dk] = *(const half8*)(kp + (size_t)(kfr * 16 + lr) * 1024
                                                   + (h0 + hh) * 64 + dk * 32 + lh * 8);
            f32x4 sc[2] = {};
#pragma unroll
            for (int kfr = 0; kfr < 2; kfr++)
#pragma unroll
                for (int dk = 0; dk < 2; dk++)
                    sc[kfr] = __builtin_amdgcn_mfma_f32_16x16x32_f16(
                        qf[hh][dk], kfh[kfr][dk], sc[kfr], 0, 0, 0);
#pragma unroll
            for (int j = 0; j < 4; j++)
                sl[hh][j] += __builtin_amdgcn_exp2f(sc[0][j])
                           + __builtin_amdgcn_exp2f(sc[1][j]);
        }
    }
#pragma unroll
    for (int hh = 0; hh < 2; hh++)
#pragma unroll
        for (int j = 0; j < 4; j++) {
            float s = sl[hh][j];
#pragma unroll
            for (int d = 1; d < 16; d <<= 1)
                s += __shfl_xor(s, d, 64);
            if (lr == hh)
                sl_p[(size_t)((ks * 4 + b) * 16 + h0 + hh) * 2048 + q0 + lh * 4 + j] = s;
        }
}

// ---- Emit kernel: p, attn_mean, O partials. Grid 1024 (k-split x q-tiles). ----
__global__ __launch_bounds__(512, 6)
void emit_kernel(const _Float16* __restrict__ Qh, const _Float16* __restrict__ Kh,
                 const _Float16* __restrict__ VT, const float* __restrict__ sl_p,
                 float* __restrict__ attn_out, _Float16* __restrict__ Op)
{
    const int blk = blockIdx.x;
    const int b = blk & 3;
    const int ks = (blk >> 2) & 1;
    const int q0 = (blk >> 3) << 4;
    const int tid = threadIdx.x;
    const int l = tid & 63, w = tid >> 6;
    const int lr = l & 15, lh = l >> 4;
    const int h0 = w << 1;

    __shared__ float pw[8][16][34];
    __shared__ _Float16 Pld[8][16][44];

    const size_t base = (size_t)b * 2048 * 1024;
    const _Float16* Qb = Qh + base;
    const _Float16* Kb = Kh + base;

    half8 qf[2][2];
#pragma unroll
    for (int hh = 0; hh < 2; hh++)
#pragma unroll
        for (int dk = 0; dk < 2; dk++)
            qf[hh][dk] = *(const half8*)(Qb + (size_t)(q0 + lr) * 1024
                                         + (h0 + hh) * 64 + dk * 32 + lh * 8);

    // reciprocal denominators from the two k-half partials
    float rinv[2][4];
#pragma unroll
    for (int hh = 0; hh < 2; hh++)
#pragma unroll
        for (int j = 0; j < 4; j++) {
            int q = q0 + lh * 4 + j;
            float s0 = sl_p[(size_t)((b) * 16 + h0 + hh) * 2048 + q];
            float s1 = sl_p[(size_t)((4 + b) * 16 + h0 + hh) * 2048 + q];
            rinv[hh][j] = 1.0f / (s0 + s1);
        }

    f32x4 oacc[2][4] = {};
    const int kend = ks * 32 + 32;
    for (int kt = ks * 32; kt < kend; kt++) {
        const int krow = kt * 32;
        const _Float16* kp = Kb + (size_t)krow * 1024;
        half8 vf[4];
#pragma unroll
        for (int dv = 0; dv < 4; dv++)
            vf[dv] = *(const half8*)(VT + (((size_t)(b * 64 + dv * 16 + lr)) << 11) + krow + lh * 8);

        float psum[2][4] = {};
#pragma unroll
        for (int hh = 0; hh < 2; hh++) {
            half8 kfh[2][2];
#pragma unroll
            for (int kfr = 0; kfr < 2; kfr++)
#pragma unroll
                for (int dk = 0; dk < 2; dk++)
                    kfh[kfr][dk] = *(const half8*)(kp + (size_t)(kfr * 16 + lr) * 1024
                                                   + (h0 + hh) * 64 + dk * 32 + lh * 8);
            f32x4 sc[2] = {};
#pragma unroll
            for (int kfr = 0; kfr < 2; kfr++)
#pragma unroll
                for (int dk = 0; dk < 2; dk++)
                    sc[kfr] = __builtin_amdgcn_mfma_f32_16x16x32_f16(
                        qf[hh][dk], kfh[kfr][dk], sc[kfr], 0, 0, 0);
#pragma unroll
            for (int kfr = 0; kfr < 2; kfr++)
#pragma unroll
                for (int j = 0; j < 4; j++) {
                    float p = __builtin_amdgcn_exp2f(sc[kfr][j]) * rinv[hh][j];
                    psum[kfr][j] += p;
                    Pld[w][lh * 4 + j][kfr * 16 + lr] = (_Float16)p;
                }
            union { half8 v8; half4 v4[2]; } pu;
            pu.v4[0] = *(const half4*)&Pld[w][lr][lh * 8];
            pu.v4[1] = *(const half4*)&Pld[w][lr][lh * 8 + 4];
            half8 pa = pu.v8;
#pragma unroll
            for (int dv = 0; dv < 4; dv++)
                oacc[hh][dv] = __builtin_amdgcn_mfma_f32_16x16x32_f16(
                    pa, vf[dv], oacc[hh][dv], 0, 0, 0);
        }
#pragma unroll
        for (int kfr = 0; kfr < 2; kfr++)
#pragma unroll
            for (int j = 0; j < 4; j++)
                pw[w][lh * 4 + j][kfr * 16 + lr] = psum[kfr][j];
        __syncthreads();
        {
            int r = tid >> 5, c = tid & 31;
            float s = 0.f;
#pragma unroll
            for (int ww = 0; ww < 8; ww++) s += pw[ww][r][c];
            attn_out[(((size_t)(b * 2048 + q0 + r)) << 11) + krow + c] = s * 0.0625f;
        }
        __syncthreads();
    }

    // O partial for this k-half (f16); Wo-GEMM sums the two halves during staging
    _Float16* op = Op + (size_t)ks * 8388608 + base;
#pragma unroll
    for (int hh = 0; hh < 2; hh++)
#pragma unroll
        for (int dv = 0; dv < 4; dv++)
#pragma unroll
            for (int j = 0; j < 4; j++) {
                int row = q0 + lh * 4 + j;
                int col = (h0 + hh) * 64 + dv * 16 + lr;
                op[(size_t)row * 1024 + col] = (_Float16)oacc[hh][dv][j];
            }
}

extern "C" void kernel_launch(void* const* d_in, const int* in_sizes, int n_in,
                              void* d_out, int out_size, void* d_ws, size_t ws_size,
                              hipStream_t stream)
{
    const float* q  = (const float*)d_in[0];
    const float* k  = (const float*)d_in[1];
    const float* v  = (const float*)d_in[2];
    const float* Wq = (const float*)d_in[3];
    const float* bq = (const float*)d_in[4];
    const float* Wk = (const float*)d_in[5];
    const float* bk = (const float*)d_in[6];
    const float* Wv = (const float*)d_in[7];
    const float* bv = (const float*)d_in[8];
    const float* Wo = (const float*)d_in[9];
    const float* bo = (const float*)d_in[10];

    float* y = (float*)d_out;
    float* attn_mean = y + (size_t)4 * 2048 * 1024;

    uint8_t* ws = (uint8_t*)d_ws;
    _Float16* Qh  = (_Float16*)(ws);                              // 16 MB
    _Float16* Kh  = (_Float16*)(ws + (size_t)16 * 1024 * 1024);   // 16 MB
    _Float16* VT  = (_Float16*)(ws + (size_t)32 * 1024 * 1024);   // 1 MB
    _Float16* Op  = (_Float16*)(ws + (size_t)34 * 1024 * 1024);   // 32 MB (2 k-half partials)
    float*    slp = (float*)   (ws + (size_t)66 * 1024 * 1024);   // 2 MB

    const float QS = 0.125f * 1.44269504088896340736f;

    gemm_bt<128, 128, 2, 2, 0, true, false><<<dim3(8, 64), dim3(256), 0, stream>>>(
        q, nullptr, Wq, bq, QS, Qh, 8192, 1024, 1024);
    gemm_bt<128, 128, 2, 2, 0, true, false><<<dim3(8, 64), dim3(256), 0, stream>>>(
        k, nullptr, Wk, bk, 1.0f, Kh, 8192, 1024, 1024);
    gemm_bt<128, 64, 4, 1, 0, true, true><<<dim3(1, 64), dim3(256), 0, stream>>>(
        v, nullptr, Wv, bv, 1.0f, VT, 8192, 64, 1024);
    stats_kernel<<<dim3(1024), dim3(512), 0, stream>>>(Qh, Kh, slp);
    emit_kernel<<<dim3(1024), dim3(512), 0, stream>>>(Qh, Kh, VT, slp, attn_mean, Op);
    gemm_bt<128, 128, 2, 2, 2, false, false><<<dim3(8, 64), dim3(256), 0, stream>>>(
        Op, Op + (size_t)8388608, Wo, bo, 1.0f, y, 8192, 1024, 1024);
}

// Round 5
// 982.463 us; speedup vs baseline: 1.1546x; 1.1546x over previous
//
#include <hip/hip_runtime.h>
#include <cstdint>
#include <cstddef>

typedef __attribute__((ext_vector_type(8))) _Float16 half8;
typedef __attribute__((ext_vector_type(4))) _Float16 half4;
typedef __attribute__((ext_vector_type(4))) float f32x4;

#define DEV static __device__ __forceinline__
#define AS1(p) (const __attribute__((address_space(1))) void*)(p)
#define AS3(p) (__attribute__((address_space(3))) void*)(p)

DEV half8 cvt8(const float* p) {
    f32x4 a = *(const f32x4*)p;
    f32x4 b = *(const f32x4*)(p + 4);
    half8 o;
    o[0] = (_Float16)a[0]; o[1] = (_Float16)a[1];
    o[2] = (_Float16)a[2]; o[3] = (_Float16)a[3];
    o[4] = (_Float16)b[0]; o[5] = (_Float16)b[1];
    o[6] = (_Float16)b[2]; o[7] = (_Float16)b[3];
    return o;
}

// ---- elementwise f32 -> f16 ----
__global__ __launch_bounds__(256)
void cvt_kernel(const float* __restrict__ in, _Float16* __restrict__ out, int n8)
{
    int i = blockIdx.x * 256 + threadIdx.x;
    int stride = gridDim.x * 256;
    for (; i < n8; i += stride)
        ((half8*)out)[i] = cvt8(in + (size_t)i * 8);
}

// ---- elementwise f16+f16 -> f16 (in-place safe: out may alias a) ----
__global__ __launch_bounds__(256)
void opsum_kernel(const _Float16* __restrict__ a, const _Float16* __restrict__ b,
                  _Float16* __restrict__ out, int n8)
{
    int i = blockIdx.x * 256 + threadIdx.x;
    int stride = gridDim.x * 256;
    for (; i < n8; i += stride) {
        half8 x = ((const half8*)a)[i];
        half8 y = ((const half8*)b)[i];
        half8 o;
#pragma unroll
        for (int j = 0; j < 8; j++) o[j] = (_Float16)((float)x[j] + (float)y[j]);
        ((half8*)out)[i] = o;
    }
}

// ---- f16 GEMM with global_load_lds staging ----
// C[M,N] = (A[M,K] @ B[N,K]^T + bias) * scale.
// 128x128 tile, BK=32, 4 waves (64x64 each), double-buffered LDS.
// LDS layout: chunk-transposed [c][128] 16-B slots -> linear gll writes,
// conflict-free ds_read_b128 (slot%8 == lr%8 spreads all 8 bank-quads).
// Grid dim3(M/128, N/128): consecutive ids share B-panel per XCD.
template<bool OUT_F16>
__global__ __launch_bounds__(256, 2)
void gemm16(const _Float16* __restrict__ A, const _Float16* __restrict__ B,
            const float* __restrict__ bias, float scale, void* __restrict__ Cout,
            int M, int N, int K)
{
    __shared__ half8 As[2][512];
    __shared__ half8 Bs[2][512];
    const int tid = threadIdx.x, l = tid & 63, w = tid >> 6;
    const int lr = l & 15, lh = l >> 4;
    const int wm0 = (w >> 1) * 64, wn0 = (w & 1) * 64;
    const int bm0 = blockIdx.x * 128, bn0 = blockIdx.y * 128;
    const int nsteps = K >> 5;

    f32x4 acc[4][4] = {};

    // stage(buf, t): wave w stages chunk-column c=w, rows q2*64+l (16 B/lane)
#define STAGE(buf, t) do {                                                        \
        int k0 = (t) << 5;                                                        \
        _Pragma("unroll")                                                         \
        for (int q2 = 0; q2 < 2; q2++) {                                          \
            int r = q2 * 64 + l;                                                  \
            __builtin_amdgcn_global_load_lds(                                     \
                AS1(A + (size_t)(bm0 + r) * K + k0 + w * 8),                      \
                AS3(&As[buf][w * 128 + q2 * 64]), 16, 0, 0);                      \
            __builtin_amdgcn_global_load_lds(                                     \
                AS1(B + (size_t)(bn0 + r) * K + k0 + w * 8),                      \
                AS3(&Bs[buf][w * 128 + q2 * 64]), 16, 0, 0);                      \
        }                                                                         \
    } while (0)

    STAGE(0, 0);
    __syncthreads();
    for (int t = 0; t < nsteps; t++) {
        int cur = t & 1;
        if (t + 1 < nsteps) STAGE(cur ^ 1, t + 1);
        half8 a[4], b[4];
#pragma unroll
        for (int m = 0; m < 4; m++) a[m] = As[cur][lh * 128 + wm0 + m * 16 + lr];
#pragma unroll
        for (int n = 0; n < 4; n++) b[n] = Bs[cur][lh * 128 + wn0 + n * 16 + lr];
#pragma unroll
        for (int m = 0; m < 4; m++)
#pragma unroll
            for (int n = 0; n < 4; n++)
                acc[m][n] = __builtin_amdgcn_mfma_f32_16x16x32_f16(a[m], b[n], acc[m][n], 0, 0, 0);
        __syncthreads();
    }
#undef STAGE

#pragma unroll
    for (int m = 0; m < 4; m++)
#pragma unroll
        for (int n = 0; n < 4; n++) {
            int row0 = bm0 + wm0 + m * 16 + lh * 4;
            int col = bn0 + wn0 + n * 16 + lr;
            float bv = bias[col];
#pragma unroll
            for (int j = 0; j < 4; j++) {
                float val = (acc[m][n][j] + bv) * scale;
                int row = row0 + j;
                if constexpr (OUT_F16)
                    ((_Float16*)Cout)[(size_t)row * N + col] = (_Float16)val;
                else
                    ((float*)Cout)[(size_t)row * N + col] = val;
            }
        }
}

// ---- legacy GEMM (f32 inputs, cvt during staging) -- used for V projection ----
// OUT_TRANS: writes f16 VT[b][n][t] with b=row>>11, t=row&2047.
template<int BM, int BN, int WR, int WC>
__global__ __launch_bounds__(256, 2)
void gemm_vp(const float* __restrict__ Aptr, const float* __restrict__ Bw,
             const float* __restrict__ bias, _Float16* __restrict__ Cout, int M, int N, int K)
{
    constexpr int BK = 32;
    constexpr int WM = BM / WR, WN = BN / WC;
    constexpr int MF = WM / 16, NF = WN / 16;
    constexpr int LDT = 40;
    __shared__ _Float16 Asl[BM][LDT];
    __shared__ _Float16 Bsl[BN][LDT];

    const int tid = threadIdx.x;
    const int l = tid & 63;
    const int w = tid >> 6;
    const int wr = w / WC, wc = w % WC;
    const int lr = l & 15, lh = l >> 4;
    const int bm0 = blockIdx.y * BM, bn0 = blockIdx.x * BN;

    f32x4 acc[MF][NF] = {};

    for (int k0 = 0; k0 < K; k0 += BK) {
        __syncthreads();
        for (int c = tid; c < BM * 4; c += 256) {
            int row = c >> 2, c8 = (c & 3) << 3;
            *(half8*)&Asl[row][c8] = cvt8(Aptr + (size_t)(bm0 + row) * K + k0 + c8);
        }
        for (int c = tid; c < BN * 4; c += 256) {
            int row = c >> 2, c8 = (c & 3) << 3;
            *(half8*)&Bsl[row][c8] = cvt8(Bw + (size_t)(bn0 + row) * K + k0 + c8);
        }
        __syncthreads();

        half8 a[MF], b[NF];
#pragma unroll
        for (int m = 0; m < MF; m++)
            a[m] = *(const half8*)&Asl[wr * WM + m * 16 + lr][lh * 8];
#pragma unroll
        for (int n = 0; n < NF; n++)
            b[n] = *(const half8*)&Bsl[wc * WN + n * 16 + lr][lh * 8];
#pragma unroll
        for (int m = 0; m < MF; m++)
#pragma unroll
            for (int n = 0; n < NF; n++)
                acc[m][n] = __builtin_amdgcn_mfma_f32_16x16x32_f16(a[m], b[n], acc[m][n], 0, 0, 0);
    }

#pragma unroll
    for (int m = 0; m < MF; m++)
#pragma unroll
        for (int n = 0; n < NF; n++) {
            int row0 = bm0 + wr * WM + m * 16 + lh * 4;
            int col = bn0 + wc * WN + n * 16 + lr;
            float bv = bias[col];
#pragma unroll
            for (int j = 0; j < 4; j++) {
                float val = acc[m][n][j] + bv;
                int row = row0 + j;
                int bi = row >> 11, t = row & 2047;
                Cout[(((size_t)(bi * 64 + col)) << 11) + t] = (_Float16)val;
            }
        }
}

// ---- Fused attention, k-split=2 with redundant phase-1 ----
// Q pre-scaled by 0.125*log2(e) -> softmax in exp2 domain; no max (scores small).
// Grid 512 = 4b x 2ks x 64 q-tiles; blk%8 = (b,ks) -> one 2MB K-half per XCD L2;
// grid == 2 blocks/CU resident -> lockstep K sweep (R1's FETCH=40MB regime).
// Phase 1: full-K denominator (redundant across the ks pair, no cross-block sync).
// Phase 2: own k-half only: p -> attn_mean (nontemporal), P->PV MFMA, O partial.
__global__ __launch_bounds__(512, 4)
void attn_kernel(const _Float16* __restrict__ Qh, const _Float16* __restrict__ Kh,
                 const _Float16* __restrict__ VT, float* __restrict__ attn_out,
                 _Float16* __restrict__ Op)
{
    const int blk = blockIdx.x;
    const int b = blk & 3;
    const int ks = (blk >> 2) & 1;
    const int q0 = (blk >> 3) << 5;
    const int tid = threadIdx.x;
    const int l = tid & 63, w = tid >> 6;
    const int lr = l & 15, lh = l >> 4;
    const int h0 = w << 1;

    __shared__ float pw[8][32][34];
    __shared__ _Float16 Pld[8][32][44];

    const size_t base = (size_t)b * 2048 * 1024;
    const _Float16* Qb = Qh + base;
    const _Float16* Kb = Kh + base;

    // Q fragments: [head][mfrag][dk]
    half8 qf[2][2][2];
#pragma unroll
    for (int hh = 0; hh < 2; hh++)
#pragma unroll
        for (int m = 0; m < 2; m++)
#pragma unroll
            for (int dk = 0; dk < 2; dk++)
                qf[hh][m][dk] = *(const half8*)(Qb + (size_t)(q0 + m * 16 + lr) * 1024
                                                + (h0 + hh) * 64 + dk * 32 + lh * 8);

    // ---- Phase 1: full-K denominators (redundant in ks pair) ----
    float sl[2][2][4] = {};
    for (int kt = 0; kt < 64; kt++) {
        const _Float16* kp = Kb + (size_t)(kt * 32) * 1024;
#pragma unroll
        for (int hh = 0; hh < 2; hh++) {
            half8 kfh[2][2];
#pragma unroll
            for (int kfr = 0; kfr < 2; kfr++)
#pragma unroll
                for (int dk = 0; dk < 2; dk++)
                    kfh[kfr][dk] = *(const half8*)(kp + (size_t)(kfr * 16 + lr) * 1024
                                                   + (h0 + hh) * 64 + dk * 32 + lh * 8);
#pragma unroll
            for (int m = 0; m < 2; m++) {
                f32x4 sc[2] = {};
#pragma unroll
                for (int kfr = 0; kfr < 2; kfr++)
#pragma unroll
                    for (int dk = 0; dk < 2; dk++)
                        sc[kfr] = __builtin_amdgcn_mfma_f32_16x16x32_f16(
                            qf[hh][m][dk], kfh[kfr][dk], sc[kfr], 0, 0, 0);
#pragma unroll
                for (int j = 0; j < 4; j++)
                    sl[hh][m][j] += __builtin_amdgcn_exp2f(sc[0][j])
                                  + __builtin_amdgcn_exp2f(sc[1][j]);
            }
        }
    }
    float rinv[2][2][4];
#pragma unroll
    for (int hh = 0; hh < 2; hh++)
#pragma unroll
        for (int m = 0; m < 2; m++)
#pragma unroll
            for (int j = 0; j < 4; j++) {
                float s = sl[hh][m][j];
#pragma unroll
                for (int d = 1; d < 16; d <<= 1)
                    s += __shfl_xor(s, d, 64);
                rinv[hh][m][j] = 1.0f / s;
            }

    // ---- Phase 2: emit own k-half ----
    f32x4 oacc[2][2][4] = {};
    __syncthreads();

    const int kt0 = ks * 32, kt1 = kt0 + 32;
    for (int kt = kt0; kt < kt1; kt++) {
        const int krow = kt * 32;
        const _Float16* kp = Kb + (size_t)krow * 1024;
        half8 vf[4];
#pragma unroll
        for (int dv = 0; dv < 4; dv++)
            vf[dv] = *(const half8*)(VT + (((size_t)(b * 64 + dv * 16 + lr)) << 11) + krow + lh * 8);

        float psum[2][2][4] = {};
#pragma unroll
        for (int hh = 0; hh < 2; hh++) {
            half8 kfh[2][2];
#pragma unroll
            for (int kfr = 0; kfr < 2; kfr++)
#pragma unroll
                for (int dk = 0; dk < 2; dk++)
                    kfh[kfr][dk] = *(const half8*)(kp + (size_t)(kfr * 16 + lr) * 1024
                                                   + (h0 + hh) * 64 + dk * 32 + lh * 8);
            f32x4 sc[2][2] = {};
#pragma unroll
            for (int m = 0; m < 2; m++)
#pragma unroll
                for (int kfr = 0; kfr < 2; kfr++)
#pragma unroll
                    for (int dk = 0; dk < 2; dk++)
                        sc[m][kfr] = __builtin_amdgcn_mfma_f32_16x16x32_f16(
                            qf[hh][m][dk], kfh[kfr][dk], sc[m][kfr], 0, 0, 0);
#pragma unroll
            for (int m = 0; m < 2; m++)
#pragma unroll
                for (int kfr = 0; kfr < 2; kfr++)
#pragma unroll
                    for (int j = 0; j < 4; j++) {
                        float p = __builtin_amdgcn_exp2f(sc[m][kfr][j]) * rinv[hh][m][j];
                        psum[m][kfr][j] += p;
                        Pld[w][m * 16 + lh * 4 + j][kfr * 16 + lr] = (_Float16)p;
                    }
#pragma unroll
            for (int m = 0; m < 2; m++) {
                union { half8 v8; half4 v4[2]; } pu;
                pu.v4[0] = *(const half4*)&Pld[w][m * 16 + lr][lh * 8];
                pu.v4[1] = *(const half4*)&Pld[w][m * 16 + lr][lh * 8 + 4];
                half8 pa = pu.v8;
#pragma unroll
                for (int dv = 0; dv < 4; dv++)
                    oacc[hh][m][dv] = __builtin_amdgcn_mfma_f32_16x16x32_f16(
                        pa, vf[dv], oacc[hh][m][dv], 0, 0, 0);
            }
        }
        // head-sum partials -> LDS -> deterministic tree reduce -> attn_mean (nt store)
#pragma unroll
        for (int m = 0; m < 2; m++)
#pragma unroll
            for (int kfr = 0; kfr < 2; kfr++)
#pragma unroll
                for (int j = 0; j < 4; j++)
                    pw[w][m * 16 + lh * 4 + j][kfr * 16 + lr] = psum[m][kfr][j];
        __syncthreads();
        for (int idx = tid; idx < 1024; idx += 512) {
            int r = idx >> 5, c = idx & 31;
            float s = 0.f;
#pragma unroll
            for (int ww = 0; ww < 8; ww++) s += pw[ww][r][c];
            __builtin_nontemporal_store(s * 0.0625f,
                &attn_out[(((size_t)(b * 2048 + q0 + r)) << 11) + krow + c]);
        }
        __syncthreads();
    }

    // O partial for this k-half (f16)
    _Float16* op = Op + (size_t)ks * 8388608 + base;
#pragma unroll
    for (int hh = 0; hh < 2; hh++)
#pragma unroll
        for (int m = 0; m < 2; m++)
#pragma unroll
            for (int dv = 0; dv < 4; dv++)
#pragma unroll
                for (int j = 0; j < 4; j++) {
                    int row = q0 + m * 16 + lh * 4 + j;
                    int col = (h0 + hh) * 64 + dv * 16 + lr;
                    op[(size_t)row * 1024 + col] = (_Float16)oacc[hh][m][dv][j];
                }
}

extern "C" void kernel_launch(void* const* d_in, const int* in_sizes, int n_in,
                              void* d_out, int out_size, void* d_ws, size_t ws_size,
                              hipStream_t stream)
{
    const float* q  = (const float*)d_in[0];
    const float* k  = (const float*)d_in[1];
    const float* v  = (const float*)d_in[2];
    const float* Wq = (const float*)d_in[3];
    const float* bq = (const float*)d_in[4];
    const float* Wk = (const float*)d_in[5];
    const float* bk = (const float*)d_in[6];
    const float* Wv = (const float*)d_in[7];
    const float* bv = (const float*)d_in[8];
    const float* Wo = (const float*)d_in[9];
    const float* bo = (const float*)d_in[10];

    float* y = (float*)d_out;
    float* attn_mean = y + (size_t)4 * 2048 * 1024;

    uint8_t* ws = (uint8_t*)d_ws;
    _Float16* Qh  = (_Float16*)(ws);                         // 16 MB @ 0
    _Float16* Kh  = (_Float16*)(ws + 16777216);              // 16 MB
    _Float16* VT  = (_Float16*)(ws + 33554432);              // 1 MB
    _Float16* Wqc = (_Float16*)(ws + 34603008);              // 2 MB
    _Float16* Wkc = (_Float16*)(ws + 36700160);              // 2 MB
    _Float16* Woc = (_Float16*)(ws + 38797312);              // 2 MB
    _Float16* qc  = (_Float16*)(ws + 40894464);              // 16 MB (becomes Op0/Of)
    _Float16* kc  = (_Float16*)(ws + 57671680);              // 16 MB (becomes Op1)
    _Float16* Op  = qc;                                      // Op0 @ qc, Op1 @ kc (contiguous)

    const float QS = 0.125f * 1.44269504088896340736f;

    // f32 -> f16 conversions (q,k dead after their GEMMs; regions reused as Op)
    cvt_kernel<<<dim3(1024), dim3(256), 0, stream>>>(q, qc, 1048576);
    cvt_kernel<<<dim3(1024), dim3(256), 0, stream>>>(k, kc, 1048576);
    cvt_kernel<<<dim3(512),  dim3(256), 0, stream>>>(Wq, Wqc, 131072);
    cvt_kernel<<<dim3(512),  dim3(256), 0, stream>>>(Wk, Wkc, 131072);
    cvt_kernel<<<dim3(512),  dim3(256), 0, stream>>>(Wo, Woc, 131072);

    gemm16<true><<<dim3(64, 8), dim3(256), 0, stream>>>(qc, Wqc, bq, QS, Qh, 8192, 1024, 1024);
    gemm16<true><<<dim3(64, 8), dim3(256), 0, stream>>>(kc, Wkc, bk, 1.0f, Kh, 8192, 1024, 1024);
    gemm_vp<128, 64, 4, 1><<<dim3(1, 64), dim3(256), 0, stream>>>(v, Wv, bv, VT, 8192, 64, 1024);

    attn_kernel<<<dim3(512), dim3(512), 0, stream>>>(Qh, Kh, VT, attn_mean, Op);

    // Of = Op0 + Op1 (in-place over Op0)
    opsum_kernel<<<dim3(1024), dim3(256), 0, stream>>>(Op, Op + (size_t)8388608, Op, 1048576);

    gemm16<false><<<dim3(64, 8), dim3(256), 0, stream>>>(Op, Woc, bo, 1.0f, y, 8192, 1024, 1024);
}

// Round 6
// 652.762 us; speedup vs baseline: 1.7378x; 1.5051x over previous
//
#include <hip/hip_runtime.h>
#include <cstdint>
#include <cstddef>

typedef __attribute__((ext_vector_type(8))) _Float16 half8;
typedef __attribute__((ext_vector_type(4))) _Float16 half4;
typedef __attribute__((ext_vector_type(4))) float f32x4;

#define DEV static __device__ __forceinline__
#define AS1(p) (const __attribute__((address_space(1))) void*)(p)
#define AS3(p) (__attribute__((address_space(3))) void*)(p)

DEV half8 cvt8(const float* p) {
    f32x4 a = *(const f32x4*)p;
    f32x4 b = *(const f32x4*)(p + 4);
    half8 o;
    o[0] = (_Float16)a[0]; o[1] = (_Float16)a[1];
    o[2] = (_Float16)a[2]; o[3] = (_Float16)a[3];
    o[4] = (_Float16)b[0]; o[5] = (_Float16)b[1];
    o[6] = (_Float16)b[2]; o[7] = (_Float16)b[3];
    return o;
}

// ---- elementwise f32 -> f16 ----
__global__ __launch_bounds__(256)
void cvt_kernel(const float* __restrict__ in, _Float16* __restrict__ out, int n8)
{
    int i = blockIdx.x * 256 + threadIdx.x;
    int stride = gridDim.x * 256;
    for (; i < n8; i += stride)
        ((half8*)out)[i] = cvt8(in + (size_t)i * 8);
}

// ---- elementwise f16+f16 -> f16 (in-place safe: out may alias a) ----
__global__ __launch_bounds__(256)
void opsum_kernel(const _Float16* __restrict__ a, const _Float16* __restrict__ b,
                  _Float16* __restrict__ out, int n8)
{
    int i = blockIdx.x * 256 + threadIdx.x;
    int stride = gridDim.x * 256;
    for (; i < n8; i += stride) {
        half8 x = ((const half8*)a)[i];
        half8 y = ((const half8*)b)[i];
        half8 o;
#pragma unroll
        for (int j = 0; j < 8; j++) o[j] = (_Float16)((float)x[j] + (float)y[j]);
        ((half8*)out)[i] = o;
    }
}

// ---- f16 GEMM with global_load_lds staging ----
// C[M,N] = (A[M,K] @ B[N,K]^T + bias) * scale.
// 128x128 tile, BK=32, 4 waves (64x64 each), double-buffered LDS.
template<bool OUT_F16>
__global__ __launch_bounds__(256, 2)
void gemm16(const _Float16* __restrict__ A, const _Float16* __restrict__ B,
            const float* __restrict__ bias, float scale, void* __restrict__ Cout,
            int M, int N, int K)
{
    __shared__ half8 As[2][512];
    __shared__ half8 Bs[2][512];
    const int tid = threadIdx.x, l = tid & 63, w = tid >> 6;
    const int lr = l & 15, lh = l >> 4;
    const int wm0 = (w >> 1) * 64, wn0 = (w & 1) * 64;
    const int bm0 = blockIdx.x * 128, bn0 = blockIdx.y * 128;
    const int nsteps = K >> 5;

    f32x4 acc[4][4] = {};

#define STAGE(buf, t) do {                                                        \
        int k0 = (t) << 5;                                                        \
        _Pragma("unroll")                                                         \
        for (int q2 = 0; q2 < 2; q2++) {                                          \
            int r = q2 * 64 + l;                                                  \
            __builtin_amdgcn_global_load_lds(                                     \
                AS1(A + (size_t)(bm0 + r) * K + k0 + w * 8),                      \
                AS3(&As[buf][w * 128 + q2 * 64]), 16, 0, 0);                      \
            __builtin_amdgcn_global_load_lds(                                     \
                AS1(B + (size_t)(bn0 + r) * K + k0 + w * 8),                      \
                AS3(&Bs[buf][w * 128 + q2 * 64]), 16, 0, 0);                      \
        }                                                                         \
    } while (0)

    STAGE(0, 0);
    __syncthreads();
    for (int t = 0; t < nsteps; t++) {
        int cur = t & 1;
        if (t + 1 < nsteps) STAGE(cur ^ 1, t + 1);
        half8 a[4], b[4];
#pragma unroll
        for (int m = 0; m < 4; m++) a[m] = As[cur][lh * 128 + wm0 + m * 16 + lr];
#pragma unroll
        for (int n = 0; n < 4; n++) b[n] = Bs[cur][lh * 128 + wn0 + n * 16 + lr];
#pragma unroll
        for (int m = 0; m < 4; m++)
#pragma unroll
            for (int n = 0; n < 4; n++)
                acc[m][n] = __builtin_amdgcn_mfma_f32_16x16x32_f16(a[m], b[n], acc[m][n], 0, 0, 0);
        __syncthreads();
    }
#undef STAGE

#pragma unroll
    for (int m = 0; m < 4; m++)
#pragma unroll
        for (int n = 0; n < 4; n++) {
            int row0 = bm0 + wm0 + m * 16 + lh * 4;
            int col = bn0 + wn0 + n * 16 + lr;
            float bv = bias[col];
#pragma unroll
            for (int j = 0; j < 4; j++) {
                float val = (acc[m][n][j] + bv) * scale;
                int row = row0 + j;
                if constexpr (OUT_F16)
                    ((_Float16*)Cout)[(size_t)row * N + col] = (_Float16)val;
                else
                    ((float*)Cout)[(size_t)row * N + col] = val;
            }
        }
}

// ---- legacy GEMM (f32 inputs, cvt during staging) -- V projection ----
template<int BM, int BN, int WR, int WC>
__global__ __launch_bounds__(256, 2)
void gemm_vp(const float* __restrict__ Aptr, const float* __restrict__ Bw,
             const float* __restrict__ bias, _Float16* __restrict__ Cout, int M, int N, int K)
{
    constexpr int BK = 32;
    constexpr int WM = BM / WR, WN = BN / WC;
    constexpr int MF = WM / 16, NF = WN / 16;
    constexpr int LDT = 40;
    __shared__ _Float16 Asl[BM][LDT];
    __shared__ _Float16 Bsl[BN][LDT];

    const int tid = threadIdx.x;
    const int l = tid & 63;
    const int w = tid >> 6;
    const int wr = w / WC, wc = w % WC;
    const int lr = l & 15, lh = l >> 4;
    const int bm0 = blockIdx.y * BM, bn0 = blockIdx.x * BN;

    f32x4 acc[MF][NF] = {};

    for (int k0 = 0; k0 < K; k0 += BK) {
        __syncthreads();
        for (int c = tid; c < BM * 4; c += 256) {
            int row = c >> 2, c8 = (c & 3) << 3;
            *(half8*)&Asl[row][c8] = cvt8(Aptr + (size_t)(bm0 + row) * K + k0 + c8);
        }
        for (int c = tid; c < BN * 4; c += 256) {
            int row = c >> 2, c8 = (c & 3) << 3;
            *(half8*)&Bsl[row][c8] = cvt8(Bw + (size_t)(bn0 + row) * K + k0 + c8);
        }
        __syncthreads();

        half8 a[MF], b[NF];
#pragma unroll
        for (int m = 0; m < MF; m++)
            a[m] = *(const half8*)&Asl[wr * WM + m * 16 + lr][lh * 8];
#pragma unroll
        for (int n = 0; n < NF; n++)
            b[n] = *(const half8*)&Bsl[wc * WN + n * 16 + lr][lh * 8];
#pragma unroll
        for (int m = 0; m < MF; m++)
#pragma unroll
            for (int n = 0; n < NF; n++)
                acc[m][n] = __builtin_amdgcn_mfma_f32_16x16x32_f16(a[m], b[n], acc[m][n], 0, 0, 0);
    }

#pragma unroll
    for (int m = 0; m < MF; m++)
#pragma unroll
        for (int n = 0; n < NF; n++) {
            int row0 = bm0 + wr * WM + m * 16 + lh * 4;
            int col = bn0 + wc * WN + n * 16 + lr;
            float bv = bias[col];
#pragma unroll
            for (int j = 0; j < 4; j++) {
                float val = acc[m][n][j] + bv;
                int row = row0 + j;
                int bi = row >> 11, t = row & 2047;
                Cout[(((size_t)(bi * 64 + col)) << 11) + t] = (_Float16)val;
            }
        }
}

// ---- Fused attention, k-split=2 with redundant phase-1 ----
// launch_bounds(512,2): 4 waves/SIMD -> 128-VGPR budget, NO SPILLS (R5's (512,4)
// capped VGPR at 64 -> 1.4GB scratch traffic).
// Grid 512 = 4b x 2ks x 64 q-tiles; blk%8=(b,ks) -> one 2MB K-half per XCD L2;
// 2 blocks/CU resident, lockstep K sweep.
__global__ __launch_bounds__(512, 2)
void attn_kernel(const _Float16* __restrict__ Qh, const _Float16* __restrict__ Kh,
                 const _Float16* __restrict__ VT, float* __restrict__ attn_out,
                 _Float16* __restrict__ Op)
{
    const int blk = blockIdx.x;
    const int b = blk & 3;
    const int ks = (blk >> 2) & 1;
    const int q0 = (blk >> 3) << 5;
    const int tid = threadIdx.x;
    const int l = tid & 63, w = tid >> 6;
    const int lr = l & 15, lh = l >> 4;
    const int h0 = w << 1;

    __shared__ float pw[8][32][34];
    __shared__ _Float16 Pld[8][32][44];

    const size_t base = (size_t)b * 2048 * 1024;
    const _Float16* Qb = Qh + base;
    const _Float16* Kb = Kh + base;

    // Q fragments: [head][mfrag][dk]
    half8 qf[2][2][2];
#pragma unroll
    for (int hh = 0; hh < 2; hh++)
#pragma unroll
        for (int m = 0; m < 2; m++)
#pragma unroll
            for (int dk = 0; dk < 2; dk++)
                qf[hh][m][dk] = *(const half8*)(Qb + (size_t)(q0 + m * 16 + lr) * 1024
                                                + (h0 + hh) * 64 + dk * 32 + lh * 8);

    // ---- Phase 1: full-K denominators (redundant in ks pair) ----
    float sl[2][2][4] = {};
    for (int kt = 0; kt < 64; kt++) {
        const _Float16* kp = Kb + (size_t)(kt * 32) * 1024;
#pragma unroll
        for (int hh = 0; hh < 2; hh++) {
            half8 kfh[2][2];
#pragma unroll
            for (int kfr = 0; kfr < 2; kfr++)
#pragma unroll
                for (int dk = 0; dk < 2; dk++)
                    kfh[kfr][dk] = *(const half8*)(kp + (size_t)(kfr * 16 + lr) * 1024
                                                   + (h0 + hh) * 64 + dk * 32 + lh * 8);
#pragma unroll
            for (int m = 0; m < 2; m++) {
                f32x4 sc[2] = {};
#pragma unroll
                for (int kfr = 0; kfr < 2; kfr++)
#pragma unroll
                    for (int dk = 0; dk < 2; dk++)
                        sc[kfr] = __builtin_amdgcn_mfma_f32_16x16x32_f16(
                            qf[hh][m][dk], kfh[kfr][dk], sc[kfr], 0, 0, 0);
#pragma unroll
                for (int j = 0; j < 4; j++)
                    sl[hh][m][j] += __builtin_amdgcn_exp2f(sc[0][j])
                                  + __builtin_amdgcn_exp2f(sc[1][j]);
            }
        }
    }
    float rinv[2][2][4];
#pragma unroll
    for (int hh = 0; hh < 2; hh++)
#pragma unroll
        for (int m = 0; m < 2; m++)
#pragma unroll
            for (int j = 0; j < 4; j++) {
                float s = sl[hh][m][j];
#pragma unroll
                for (int d = 1; d < 16; d <<= 1)
                    s += __shfl_xor(s, d, 64);
                rinv[hh][m][j] = 1.0f / s;
            }

    // ---- Phase 2: emit own k-half ----
    f32x4 oacc[2][2][4] = {};
    __syncthreads();

    const int kt0 = ks * 32, kt1 = kt0 + 32;
    for (int kt = kt0; kt < kt1; kt++) {
        const int krow = kt * 32;
        const _Float16* kp = Kb + (size_t)krow * 1024;
        half8 vf[4];
#pragma unroll
        for (int dv = 0; dv < 4; dv++)
            vf[dv] = *(const half8*)(VT + (((size_t)(b * 64 + dv * 16 + lr)) << 11) + krow + lh * 8);

        float psum[2][2][4] = {};
#pragma unroll
        for (int hh = 0; hh < 2; hh++) {
            half8 kfh[2][2];
#pragma unroll
            for (int kfr = 0; kfr < 2; kfr++)
#pragma unroll
                for (int dk = 0; dk < 2; dk++)
                    kfh[kfr][dk] = *(const half8*)(kp + (size_t)(kfr * 16 + lr) * 1024
                                                   + (h0 + hh) * 64 + dk * 32 + lh * 8);
            f32x4 sc[2][2] = {};
#pragma unroll
            for (int m = 0; m < 2; m++)
#pragma unroll
                for (int kfr = 0; kfr < 2; kfr++)
#pragma unroll
                    for (int dk = 0; dk < 2; dk++)
                        sc[m][kfr] = __builtin_amdgcn_mfma_f32_16x16x32_f16(
                            qf[hh][m][dk], kfh[kfr][dk], sc[m][kfr], 0, 0, 0);
#pragma unroll
            for (int m = 0; m < 2; m++)
#pragma unroll
                for (int kfr = 0; kfr < 2; kfr++)
#pragma unroll
                    for (int j = 0; j < 4; j++) {
                        float p = __builtin_amdgcn_exp2f(sc[m][kfr][j]) * rinv[hh][m][j];
                        psum[m][kfr][j] += p;
                        Pld[w][m * 16 + lh * 4 + j][kfr * 16 + lr] = (_Float16)p;
                    }
#pragma unroll
            for (int m = 0; m < 2; m++) {
                union { half8 v8; half4 v4[2]; } pu;
                pu.v4[0] = *(const half4*)&Pld[w][m * 16 + lr][lh * 8];
                pu.v4[1] = *(const half4*)&Pld[w][m * 16 + lr][lh * 8 + 4];
                half8 pa = pu.v8;
#pragma unroll
                for (int dv = 0; dv < 4; dv++)
                    oacc[hh][m][dv] = __builtin_amdgcn_mfma_f32_16x16x32_f16(
                        pa, vf[dv], oacc[hh][m][dv], 0, 0, 0);
            }
        }
#pragma unroll
        for (int m = 0; m < 2; m++)
#pragma unroll
            for (int kfr = 0; kfr < 2; kfr++)
#pragma unroll
                for (int j = 0; j < 4; j++)
                    pw[w][m * 16 + lh * 4 + j][kfr * 16 + lr] = psum[m][kfr][j];
        __syncthreads();
        for (int idx = tid; idx < 1024; idx += 512) {
            int r = idx >> 5, c = idx & 31;
            float s = 0.f;
#pragma unroll
            for (int ww = 0; ww < 8; ww++) s += pw[ww][r][c];
            __builtin_nontemporal_store(s * 0.0625f,
                &attn_out[(((size_t)(b * 2048 + q0 + r)) << 11) + krow + c]);
        }
        __syncthreads();
    }

    // O partial for this k-half (f16)
    _Float16* op = Op + (size_t)ks * 8388608 + base;
#pragma unroll
    for (int hh = 0; hh < 2; hh++)
#pragma unroll
        for (int m = 0; m < 2; m++)
#pragma unroll
            for (int dv = 0; dv < 4; dv++)
#pragma unroll
                for (int j = 0; j < 4; j++) {
                    int row = q0 + m * 16 + lh * 4 + j;
                    int col = (h0 + hh) * 64 + dv * 16 + lr;
                    op[(size_t)row * 1024 + col] = (_Float16)oacc[hh][m][dv][j];
                }
}

extern "C" void kernel_launch(void* const* d_in, const int* in_sizes, int n_in,
                              void* d_out, int out_size, void* d_ws, size_t ws_size,
                              hipStream_t stream)
{
    const float* q  = (const float*)d_in[0];
    const float* k  = (const float*)d_in[1];
    const float* v  = (const float*)d_in[2];
    const float* Wq = (const float*)d_in[3];
    const float* bq = (const float*)d_in[4];
    const float* Wk = (const float*)d_in[5];
    const float* bk = (const float*)d_in[6];
    const float* Wv = (const float*)d_in[7];
    const float* bv = (const float*)d_in[8];
    const float* Wo = (const float*)d_in[9];
    const float* bo = (const float*)d_in[10];

    float* y = (float*)d_out;
    float* attn_mean = y + (size_t)4 * 2048 * 1024;

    uint8_t* ws = (uint8_t*)d_ws;
    _Float16* Qh  = (_Float16*)(ws);                         // 16 MB @ 0
    _Float16* Kh  = (_Float16*)(ws + 16777216);              // 16 MB
    _Float16* VT  = (_Float16*)(ws + 33554432);              // 1 MB
    _Float16* Wqc = (_Float16*)(ws + 34603008);              // 2 MB
    _Float16* Wkc = (_Float16*)(ws + 36700160);              // 2 MB
    _Float16* Woc = (_Float16*)(ws + 38797312);              // 2 MB
    _Float16* qc  = (_Float16*)(ws + 40894464);              // 16 MB (becomes Op0/Of)
    _Float16* kc  = (_Float16*)(ws + 57671680);              // 16 MB (becomes Op1)
    _Float16* Op  = qc;                                      // Op0 @ qc, Op1 @ kc (contiguous)

    const float QS = 0.125f * 1.44269504088896340736f;

    cvt_kernel<<<dim3(1024), dim3(256), 0, stream>>>(q, qc, 1048576);
    cvt_kernel<<<dim3(1024), dim3(256), 0, stream>>>(k, kc, 1048576);
    cvt_kernel<<<dim3(512),  dim3(256), 0, stream>>>(Wq, Wqc, 131072);
    cvt_kernel<<<dim3(512),  dim3(256), 0, stream>>>(Wk, Wkc, 131072);
    cvt_kernel<<<dim3(512),  dim3(256), 0, stream>>>(Wo, Woc, 131072);

    gemm16<true><<<dim3(64, 8), dim3(256), 0, stream>>>(qc, Wqc, bq, QS, Qh, 8192, 1024, 1024);
    gemm16<true><<<dim3(64, 8), dim3(256), 0, stream>>>(kc, Wkc, bk, 1.0f, Kh, 8192, 1024, 1024);
    gemm_vp<128, 64, 4, 1><<<dim3(1, 64), dim3(256), 0, stream>>>(v, Wv, bv, VT, 8192, 64, 1024);

    attn_kernel<<<dim3(512), dim3(512), 0, stream>>>(Qh, Kh, VT, attn_mean, Op);

    opsum_kernel<<<dim3(1024), dim3(256), 0, stream>>>(Op, Op + (size_t)8388608, Op, 1048576);

    gemm16<false><<<dim3(64, 8), dim3(256), 0, stream>>>(Op, Woc, bo, 1.0f, y, 8192, 1024, 1024);
}